// Round 13
// baseline (126.160 us; speedup 1.0000x reference)
//
#include <hip/hip_runtime.h>

// KMeans soft-assignment via bf16 hi/lo split MFMA (3 passes), fused softmax.
// logits = (2*x.c - ||c||^2)/T, T=0.1; ||x||^2 cancels in softmax.
// R13: occupancy push. Wave = 32x64 (acc=32 AGPR), 8-wave/512-thr blocks,
// BM=32, launch_bounds(512,4) targeting <=128 regs -> 16 waves/CU (2 indep
// blocks/CU). A tile pre-converted to hi/lo bf16 in LDS once (coalesced,
// XOR-swizzled), K-loop: 2 ds_read + 4 register-direct B loads + 6 MFMA.
// x: [32768,256] f32, c: [512,256] f32, out: [32768,512] f32
#define NROWS 32768
#define KC 512
#define DDIM 256
#define BM 32
#define BK 16
#define KCH (DDIM / BK)        // 16 k-chunks
#define CHUNK_USH (KC * BK)    // 8192 ushorts = 16 KB per chunk table

typedef __attribute__((ext_vector_type(8)))  short bf16x8;
typedef __attribute__((ext_vector_type(16))) float f32x16;

union U8 { unsigned short u[8]; bf16x8 v; };

__device__ __forceinline__ unsigned short f2bf(float f) {   // RNE f32->bf16
    union { float f; unsigned int u; } a; a.f = f;
    unsigned int r = a.u + 0x7fffu + ((a.u >> 16) & 1u);
    return (unsigned short)(r >> 16);
}
__device__ __forceinline__ float bf2f(unsigned short h) {
    union { unsigned int u; float f; } a; a.u = ((unsigned int)h) << 16;
    return a.f;
}

// ---- prep: c -> chunk-major bf16 hi/lo tables + csq10 (same as R12, verified) ----
// octet (col n, half h) of chunk ks at ushort offset:
//   ks*CHUNK_USH + (n>>5)*512 + (h*32 + (n&31))*8
__global__ __launch_bounds__(64) void prep_c(const float* __restrict__ c,
                                             unsigned short* __restrict__ bhi,
                                             unsigned short* __restrict__ blo,
                                             float* __restrict__ csq10) {
    const int n = blockIdx.x, lane = threadIdx.x;
    const int d0 = lane * 4;
    float4 v = ((const float4*)(c + (size_t)n * DDIM))[lane];
    float vv[4] = {v.x, v.y, v.z, v.w};
    unsigned short hh[4], ll[4];
    float ssq = 0.f;
    #pragma unroll
    for (int i = 0; i < 4; ++i) {
        ssq += vv[i] * vv[i];
        hh[i] = f2bf(vv[i]);
        ll[i] = f2bf(vv[i] - bf2f(hh[i]));
    }
    #pragma unroll
    for (int off = 32; off; off >>= 1) ssq += __shfl_xor(ssq, off);
    if (lane == 0) csq10[n] = 10.f * ssq;
    const int ks = d0 >> 4;
    const int h  = (d0 >> 3) & 1;
    const int j0 = d0 & 7;
    const size_t dst = (size_t)ks * CHUNK_USH + (n >> 5) * 512 +
                       (h * 32 + (n & 31)) * 8 + j0;
    *(ushort4*)(bhi + dst) = make_ushort4(hh[0], hh[1], hh[2], hh[3]);
    *(ushort4*)(blo + dst) = make_ushort4(ll[0], ll[1], ll[2], ll[3]);
}

// ---- main: 1024 blocks x 512 threads (8 waves; wave w = rows 0..31 x cols w*64..+63) ----
union SmemU {
    unsigned short A[2][BM * 256];   // [hi/lo][row*256 + p*8 + half*4], 32 KB
    float lbuf[16 * 516];            // 33 KB transpose overlay (A dead by then)
};

__global__ __launch_bounds__(512, 4) void kmeans_mfma(
    const float* __restrict__ x, const unsigned short* __restrict__ bhi,
    const unsigned short* __restrict__ blo, const float* __restrict__ csq10,
    float* __restrict__ out) {
    __shared__ __align__(16) SmemU sm;
    __shared__ float  red0[8][BM], red1[8][BM];   // 2 KB
    __shared__ float  Mrow[BM];                   // 128 B
    __shared__ float2 MI[BM];                     // 256 B

    const int tid  = threadIdx.x;
    const int w    = tid >> 6, lane = tid & 63;
    const int c5   = lane & 31, h = lane >> 5;
    const int row0 = blockIdx.x * BM;

    f32x16 acc[2];
    #pragma unroll
    for (int t = 0; t < 2; ++t)
        #pragma unroll
        for (int r = 0; r < 16; ++r) acc[t][r] = 0.f;

    // ---- stage A tile once: 32 rows x 256 k, f32 -> hi/lo bf16, swizzled ----
    // octet o (0..31) of row r stored at slot p = o ^ r  (uniform bank spread)
    {
        const float4* x4 = (const float4*)(x + (size_t)row0 * DDIM);
        #pragma unroll
        for (int j = 0; j < 4; ++j) {
            const int fidx = j * 512 + tid;      // 0..2047 float4 slots
            const int r    = fidx >> 6;          // 0..31
            const int col4 = fidx & 63;          // float4 index in row
            float4 v = x4[fidx];
            const int o    = col4 >> 1, half = col4 & 1;
            const int p    = o ^ r;
            const int dst  = r * 256 + p * 8 + half * 4;
            float vv[4] = {v.x, v.y, v.z, v.w};
            unsigned short hh[4], ll[4];
            #pragma unroll
            for (int i = 0; i < 4; ++i) {
                hh[i] = f2bf(vv[i]);
                ll[i] = f2bf(vv[i] - bf2f(hh[i]));
            }
            *(ushort4*)&sm.A[0][dst] = make_ushort4(hh[0], hh[1], hh[2], hh[3]);
            *(ushort4*)&sm.A[1][dst] = make_ushort4(ll[0], ll[1], ll[2], ll[3]);
        }
    }
    __syncthreads();

    // B: wave owns col-tiles w*2, w*2+1; lane octet = lane*8 (prep layout)
    const unsigned short* bhB = bhi + (size_t)(w * 2) * 512 + lane * 8;
    const unsigned short* blB = blo + (size_t)(w * 2) * 512 + lane * 8;

    for (int ks = 0; ks < KCH; ++ks) {
        const size_t cb = (size_t)ks * CHUNK_USH;
        // batch-issue B loads (register-direct) + A ds_reads; fence batches them
        bf16x8 bh[2], bl[2];
        #pragma unroll
        for (int t = 0; t < 2; ++t) {
            bh[t] = *(const bf16x8*)(bhB + cb + t * 512);
            bl[t] = *(const bf16x8*)(blB + cb + t * 512);
        }
        const int po = (2 * ks + h) ^ c5;
        bf16x8 ah = *(const bf16x8*)&sm.A[0][c5 * 256 + po * 8];
        bf16x8 al = *(const bf16x8*)&sm.A[1][c5 * 256 + po * 8];
        __syncthreads();   // scheduling fence: single drain for the batch

        #pragma unroll
        for (int t = 0; t < 2; ++t) {
            acc[t] = __builtin_amdgcn_mfma_f32_32x32x16_bf16(ah, bh[t], acc[t], 0, 0, 0);
            acc[t] = __builtin_amdgcn_mfma_f32_32x32x16_bf16(ah, bl[t], acc[t], 0, 0, 0);
            acc[t] = __builtin_amdgcn_mfma_f32_32x32x16_bf16(al, bh[t], acc[t], 0, 0, 0);
        }
    }

    // ---- softmax stats; C/D: col = w*64 + t*32 + c5, row = (r&3)+8*(r>>2)+4h
    float csqv[2];
    #pragma unroll
    for (int t = 0; t < 2; ++t) csqv[t] = csq10[w * 64 + t * 32 + c5];

    #pragma unroll
    for (int r = 0; r < 16; ++r) {
        float pm = fmaxf(20.f * acc[0][r] - csqv[0], 20.f * acc[1][r] - csqv[1]);
        #pragma unroll
        for (int off = 1; off < 32; off <<= 1) pm = fmaxf(pm, __shfl_xor(pm, off));
        if (c5 == 0) red0[w][(r & 3) + 8 * (r >> 2) + 4 * h] = pm;
    }
    __syncthreads();
    if (tid < BM) {
        float m = -1e30f;
        #pragma unroll
        for (int ww = 0; ww < 8; ++ww) m = fmaxf(m, red0[ww][tid]);
        Mrow[tid] = m;
    }
    __syncthreads();
    #pragma unroll
    for (int r = 0; r < 16; ++r) {
        const int   row = (r & 3) + 8 * (r >> 2) + 4 * h;
        const float Mf  = Mrow[row];
        float ps = __expf(20.f * acc[0][r] - csqv[0] - Mf) +
                   __expf(20.f * acc[1][r] - csqv[1] - Mf);
        #pragma unroll
        for (int off = 1; off < 32; off <<= 1) ps += __shfl_xor(ps, off);
        if (c5 == 0) red1[w][row] = ps;
    }
    __syncthreads();
    if (tid < BM) {
        float s = 0.f;
        #pragma unroll
        for (int ww = 0; ww < 8; ++ww) s += red1[ww][tid];
        MI[tid] = make_float2(Mrow[tid], 1.f / s);
    }
    __syncthreads();

    // ---- transpose epilogue: 2 passes of 16 rows through lbuf (overlays A) ----
    #pragma unroll
    for (int p = 0; p < 2; ++p) {
        #pragma unroll
        for (int i = 0; i < 8; ++i) {
            const int    r  = p * 8 + i;
            const int    lr = (r & 3) + 8 * ((r >> 2) & 1) + 4 * h;   // 0..15
            const float2 mi = MI[p * 16 + lr];
            #pragma unroll
            for (int t = 0; t < 2; ++t)
                sm.lbuf[lr * 516 + w * 64 + t * 32 + c5] =
                    __expf(20.f * acc[t][r] - csqv[t] - mi.x) * mi.y;
        }
        __syncthreads();
        #pragma unroll
        for (int j = 0; j < 4; ++j) {
            const int f    = j * 512 + tid;     // 0..2047 float4 slots
            const int lrow = f >> 7;            // 0..15
            const int c4   = f & 127;
            float4    v    = *(const float4*)&sm.lbuf[lrow * 516 + c4 * 4];
            *(float4*)(out + (size_t)(row0 + p * 16 + lrow) * KC + c4 * 4) = v;
        }
        __syncthreads();
    }
}

extern "C" void kernel_launch(void* const* d_in, const int* in_sizes, int n_in,
                              void* d_out, int out_size, void* d_ws, size_t ws_size,
                              hipStream_t stream) {
    const float* x   = (const float*)d_in[0];
    const float* c   = (const float*)d_in[1];
    float*       out = (float*)d_out;

    unsigned short* bhi   = (unsigned short*)d_ws;                 // 256 KB
    unsigned short* blo   = bhi + (size_t)KCH * CHUNK_USH;         // 256 KB
    float*          csq10 = (float*)(blo + (size_t)KCH * CHUNK_USH);  // 2 KB

    prep_c<<<KC, 64, 0, stream>>>(c, bhi, blo, csq10);
    kmeans_mfma<<<NROWS / BM, 512, 0, stream>>>(x, bhi, blo, csq10, out);
}